// Round 8
// baseline (775.391 us; speedup 1.0000x reference)
//
#include <hip/hip_runtime.h>
#include <math.h>

#define NND 50000
#define DEG 16

typedef __attribute__((ext_vector_type(8))) short short8v;
typedef __attribute__((ext_vector_type(4))) float float4v;

// ---- workspace layout (bytes) ----
#define OFF_HPRE 0ULL            // N x 64 f32
#define OFF_PROJ 12800000ULL     // 4 x N x 64 f32
#define OFF_XB   64000000ULL     // N x 128 bf16
#define OFF_IDX  102400000ULL    // 5*N int
#define OFF_BQF  103600384ULL    // 4y x 8c x 8ct x 64 x 8 bf16 = 256 KB
#define OFF_WOF  103862528ULL    // 4c x 8ct x 64 x 8 bf16 = 32 KB
#define WS_NEED  103895296ULL

#define LOG2E 1.44269504088896f

__device__ __forceinline__ float fast_sig(float x){
    return __builtin_amdgcn_rcpf(1.f + __builtin_amdgcn_exp2f(-LOG2E*x));
}
__device__ __forceinline__ float fast_tanh(float x){
    return fmaf(-2.f, __builtin_amdgcn_rcpf(1.f + __builtin_amdgcn_exp2f((2.f*LOG2E)*x)), 1.f);
}
__device__ __forceinline__ unsigned short f2bf(float f){
    unsigned int u = __float_as_uint(f);
    u += 0x7FFFu + ((u >> 16) & 1u);
    return (unsigned short)(u >> 16);
}
__device__ __forceinline__ float bf2f(unsigned short h){
    return __uint_as_float(((unsigned int)h) << 16);
}

// ---------------- fused setup: iota + pack_x + pack_bqf + pack_wof ----------
// grid 6250 x 256 = 1.6M threads = NND*32 (pack_x domain); smaller tasks nest.
__global__ __launch_bounds__(256) void k_setup(const float* __restrict__ na,
    unsigned short* __restrict__ Xb,
    const float* __restrict__ Wx, const float* __restrict__ Wh,
    unsigned short* __restrict__ BqF,
    const float* __restrict__ Wo, unsigned short* __restrict__ WoF,
    int* __restrict__ idx0)
{
    int i = blockIdx.x*256 + threadIdx.x;
    if (i < NND*32){
        float4 v = *(const float4*)(na + (size_t)i*4);
        unsigned long long pk = (unsigned long long)f2bf(v.x)
            | ((unsigned long long)f2bf(v.y) << 16)
            | ((unsigned long long)f2bf(v.z) << 32)
            | ((unsigned long long)f2bf(v.w) << 48);
        *(unsigned long long*)(Xb + (size_t)i*4) = pk;
    }
    if (i < 131072){
        int jj = i & 7, lane = (i>>3)&63, ct = (i>>9)&7, c = (i>>12)&7, y = i>>15;
        int g = ct>>1, jh = ct&1, mm = lane&15, quad = lane>>4;
        int jg = (y<<5) + (jh<<4) + mm;
        int k = (c<<5) + (quad<<3) + jj;
        float v = 0.f;
        if (k < 128){
            if (g < 3) v = Wh[k*384 + g*128 + jg];
        } else {
            int kk = k - 128;
            if (g == 0)      v = Wx[kk*384 + jg];
            else if (g == 1) v = Wx[kk*384 + 128 + jg];
            else if (g == 3) v = Wx[kk*384 + 256 + jg];
        }
        BqF[i] = f2bf(v);
    }
    if (i < 16384){
        int jj = i & 7, lane = (i>>3)&63, ct = (i>>9)&7, c = i>>12;
        int n = (ct<<4) + (lane&15);
        int k = (c<<5) + ((lane>>4)<<3) + jj;
        WoF[i] = f2bf(Wo[k*128 + n]);
    }
    if (i < NND) idx0[i] = i;
}

// ---------------- walk phase (fp32, argmax determinism) ----------------
__global__ __launch_bounds__(256,4) void k_projall(const float* __restrict__ A,
    const float* __restrict__ W1, const float* __restrict__ b1,
    float* __restrict__ hpre, float* __restrict__ proj)
{
    __shared__ float Al[64][33];
    __shared__ float Bl[32][68];
    const int tid = threadIdx.x;
    const int row0 = blockIdx.x << 6;
    const int y = blockIdx.y;
    const float* B = W1 + (size_t)y*128*64;
    const int row_t = tid >> 4, col_t = tid & 15;
    float4 acc[4];
#pragma unroll
    for (int i=0;i<4;i++) acc[i] = make_float4(0.f,0.f,0.f,0.f);
    for (int k0 = 0; k0 < 128; k0 += 32){
#pragma unroll
        for (int r=0;r<2;r++){
            int am = (tid>>3) + (r<<5);
            int ak = (tid&7) << 2;
            int gr = row0 + am; if (gr >= NND) gr = NND-1;
            float4 v = *(const float4*)(A + (size_t)gr*128 + k0 + ak);
            Al[am][ak] = v.x; Al[am][ak+1] = v.y; Al[am][ak+2] = v.z; Al[am][ak+3] = v.w;
        }
#pragma unroll
        for (int r=0;r<2;r++){
            int p = (r<<8) + tid;
            int bk = p >> 4, bc = (p & 15) << 2;
            *(float4*)(&Bl[bk][bc]) = *(const float4*)(B + (size_t)(k0+bk)*64 + bc);
        }
        __syncthreads();
#pragma unroll 8
        for (int k=0;k<32;k++){
            float4 b = *(const float4*)(&Bl[k][col_t<<2]);
#pragma unroll
            for (int i=0;i<4;i++){
                float a = Al[(row_t<<2)+i][k];
                acc[i].x = fmaf(a, b.x, acc[i].x);
                acc[i].y = fmaf(a, b.y, acc[i].y);
                acc[i].z = fmaf(a, b.z, acc[i].z);
                acc[i].w = fmaf(a, b.w, acc[i].w);
            }
        }
        __syncthreads();
    }
    float4 bb = make_float4(0.f,0.f,0.f,0.f);
    if (y == 0) bb = *(const float4*)(b1 + (col_t<<2));
    float* dst = (y == 0) ? hpre : (proj + (size_t)(y-1)*NND*64);
#pragma unroll
    for (int i=0;i<4;i++){
        int gr = row0 + (row_t<<2) + i;
        if (gr < NND){
            float4 o = make_float4(acc[i].x+bb.x, acc[i].y+bb.y, acc[i].z+bb.z, acc[i].w+bb.w);
            *(float4*)(dst + (size_t)gr*64 + (col_t<<2)) = o;
        }
    }
}

// All 4 walk steps fused; 16 lanes per node; coalesced 256B proj-row gathers.
__global__ __launch_bounds__(256) void k_walk4(
    const float* __restrict__ hpre0, const float* __restrict__ proj,
    const int* __restrict__ dst, const float* __restrict__ W2,
    const float* __restrict__ b2, const float* __restrict__ noise,
    int* __restrict__ idxb)
{
    const int tid = threadIdx.x;
    const int sg = tid >> 4, l = tid & 15;
    const int gi = (blockIdx.x << 4) + sg;
    float4 hp = *(const float4*)(hpre0 + ((size_t)gi<<6) + (l<<2));
    float4 w2 = *(const float4*)(W2 + (l<<2));
    const float b2s = b2[0];
    int curv = gi;
#pragma unroll 1
    for (int t=0; t<4; t++){
        const float* pj = proj + (size_t)t*NND*64;
        const int nbr = dst[curv*DEG + l];
        float4 val[16];
#pragma unroll
        for (int d=0; d<16; d++){
            int nd = __shfl(nbr, d, 16);
            val[d] = *(const float4*)(pj + ((size_t)nd<<6) + (l<<2));
        }
        float lp = 0.f;
#pragma unroll
        for (int d=0; d<16; d++){
            float4 v = val[d];
            float q =  fmaxf(hp.x+v.x,0.f)*w2.x;
            q = fmaf(fmaxf(hp.y+v.y,0.f), w2.y, q);
            q = fmaf(fmaxf(hp.z+v.z,0.f), w2.z, q);
            q = fmaf(fmaxf(hp.w+v.w,0.f), w2.w, q);
            q += __shfl_xor(q, 1, 16);
            q += __shfl_xor(q, 2, 16);
            q += __shfl_xor(q, 4, 16);
            q += __shfl_xor(q, 8, 16);
            if (l == d) lp = q + b2s;
        }
        float mx = lp;
#pragma unroll
        for (int off=8; off; off>>=1) mx = fmaxf(mx, __shfl_xor(mx, off, 16));
        float s = expf(lp - mx);
#pragma unroll
        for (int off=8; off; off>>=1) s += __shfl_xor(s, off, 16);
        float p = expf(lp - mx - logf(s)) + noise[(size_t)t*NND*DEG + ((size_t)gi<<4) + l];
        float bv = p; int bi = l;
#pragma unroll
        for (int off=8; off; off>>=1){
            float ov = __shfl_xor(bv, off, 16);
            int   oi = __shfl_xor(bi, off, 16);
            if (ov > bv || (ov == bv && oi < bi)){ bv = ov; bi = oi; }
        }
        int sel = __shfl(nbr, bi, 16);
        if (l == 0) idxb[(size_t)(t+1)*NND + gi] = sel;
        float4 u = *(const float4*)(pj + ((size_t)sel<<6) + (l<<2));
        hp.x += u.x; hp.y += u.y; hp.z += u.z; hp.w += u.w;
        curv = sel;
    }
}

// ---------------- fully fused GRU (5 steps) + output GEMM, v3 ----------------
// 64 rows/block. h frags in A_l (16KB); x single-buffered in X_l (16KB);
// zero-gate MFMAs skipped (6 of 8 ct per chunk); h_old in registers;
// 4 blocks/CU via launch_bounds(256,4).
__global__ __launch_bounds__(256,4) void k_gru5(
    const unsigned short* __restrict__ Xb,
    const unsigned short* __restrict__ BqF,
    const unsigned short* __restrict__ WoF,
    const float* __restrict__ bx, const float* __restrict__ bh,
    const float* __restrict__ bo, const int* __restrict__ idxb,
    float* __restrict__ out)
{
    __shared__ unsigned short A_l[8192];    // h frags [rt4][c4][64][8]
    __shared__ unsigned short X_l[8192];    // x frags [rt4][c4][64][8]
    const int tid = threadIdx.x;
    const int w = tid >> 6, lane = tid & 63;
    const int m = lane & 15, quad = lane >> 4;
    const int row0 = blockIdx.x << 6;
    const int r = tid & 63, q = tid >> 6;
    int gr = row0 + r; if (gr >= NND) gr = NND-1;
    const int rt_s = r >> 4, m_s = r & 15;
    float brr[2], bzz[2], bxn[2], bhn[2];
#pragma unroll
    for (int jh=0; jh<2; jh++){
        int j = (w<<5) + (jh<<4) + m;
        brr[jh] = bx[j] + bh[j];
        bzz[jh] = bx[128+j] + bh[128+j];
        bxn[jh] = bx[256+j];
        bhn[jh] = bh[256+j];
    }
    unsigned short holdv[2][4][4];
    short8v xv[4];
    {
        const int xr = idxb[gr];
        const unsigned short* xrow = Xb + (size_t)xr*128 + (q<<5);
#pragma unroll
        for (int u=0;u<4;u++) xv[u] = *(const short8v*)(xrow + (u<<3));
#pragma unroll
        for (int u=0;u<4;u++)
            *(short8v*)(X_l + (((rt_s<<2)+q)*64 + (u<<4) + m_s)*8) = xv[u];
        const int xr1 = idxb[NND + gr];
        const unsigned short* xrow1 = Xb + (size_t)xr1*128 + (q<<5);
#pragma unroll
        for (int u=0;u<4;u++) xv[u] = *(const short8v*)(xrow1 + (u<<3));
    }
    __syncthreads();

#pragma unroll 1
    for (int s=0; s<5; s++){
        float4v zero = {0.f,0.f,0.f,0.f};
        float4v acc[32];   // [ct8][rt4]
#pragma unroll
        for (int i=0;i<32;i++) acc[i] = zero;
        const int c0 = (s == 0) ? 4 : 0;
        for (int c=c0;c<8;c++){
            const unsigned short* asrc = (c < 4) ? A_l : X_l;
            short8v afr[4];
#pragma unroll
            for (int rt=0;rt<4;rt++)
                afr[rt] = *(const short8v*)(asrc + (((rt<<2) + (c&3))*64 + lane)*8);
            const unsigned short* bp = BqF + ((((size_t)w*8 + c)*8)*64 + lane)*8;
            // skip structurally-zero gate blocks: c<4 -> ct{0..5}; c>=4 -> ct{0..3,6,7}
#pragma unroll
            for (int ci=0;ci<6;ci++){
                int ct = (ci < 4) ? ci : ((c < 4) ? ci : ci + 2);
                short8v bf = *(const short8v*)(bp + (ct<<9));
#pragma unroll
                for (int rt=0;rt<4;rt++)
                    acc[(ct<<2)+rt] = __builtin_amdgcn_mfma_f32_16x16x32_bf16(afr[rt], bf, acc[(ct<<2)+rt], 0,0,0);
            }
        }
        // epilogue: fast gates, h_old from regs
#pragma unroll
        for (int jh=0; jh<2; jh++){
#pragma unroll
            for (int rt=0; rt<4; rt++){
#pragma unroll
                for (int r4=0; r4<4; r4++){
                    float rg = fast_sig(acc[(jh<<2)+rt][r4] + brr[jh]);
                    float zg = fast_sig(acc[((2+jh)<<2)+rt][r4] + bzz[jh]);
                    float ng = fast_tanh(acc[((6+jh)<<2)+rt][r4] + bxn[jh] + rg*(acc[((4+jh)<<2)+rt][r4] + bhn[jh]));
                    float hold = (s == 0) ? 0.f : bf2f(holdv[jh][rt][r4]);
                    holdv[jh][rt][r4] = f2bf((1.f - zg)*ng + zg*hold);
                }
            }
        }
        __syncthreads();   // all A_l/X_l reads of this step done
#pragma unroll
        for (int jh=0; jh<2; jh++)
#pragma unroll
            for (int rt=0; rt<4; rt++)
#pragma unroll
                for (int r4=0; r4<4; r4++){
                    int ha = ((((rt<<2)+w)*64 + (((jh<<1)+(m>>3))<<4) + (quad<<2)+r4)<<3) + (m&7);
                    A_l[ha] = holdv[jh][rt][r4];
                }
        if (s < 4){
#pragma unroll
            for (int u=0;u<4;u++)
                *(short8v*)(X_l + (((rt_s<<2)+q)*64 + (u<<4) + m_s)*8) = xv[u];
            if (s < 3){
                const int xr = idxb[(size_t)(s+2)*NND + gr];
                const unsigned short* xrow = Xb + (size_t)xr*128 + (q<<5);
#pragma unroll
                for (int u=0;u<4;u++) xv[u] = *(const short8v*)(xrow + (u<<3));
            }
        }
        __syncthreads();   // A_l/X_l ready for next step / out-GEMM
    }
    // output GEMM: wave w -> cols (w<<5)..(w<<5)+31, K=128
    float4v zero = {0.f,0.f,0.f,0.f};
    float4v acco[8];   // [cto2][rt4]
#pragma unroll
    for (int i=0;i<8;i++) acco[i] = zero;
    for (int c=0;c<4;c++){
        short8v afr[4];
#pragma unroll
        for (int rt=0;rt<4;rt++)
            afr[rt] = *(const short8v*)(A_l + (((rt<<2) + c)*64 + lane)*8);
#pragma unroll
        for (int cto=0;cto<2;cto++){
            short8v bf = *(const short8v*)(WoF + (((size_t)(c*8 + (w<<1)+cto))*64 + lane)*8);
#pragma unroll
            for (int rt=0;rt<4;rt++)
                acco[(cto<<2)+rt] = __builtin_amdgcn_mfma_f32_16x16x32_bf16(afr[rt], bf, acco[(cto<<2)+rt], 0,0,0);
        }
    }
#pragma unroll
    for (int cto=0; cto<2; cto++){
        int col = (w<<5) + (cto<<4) + m;
        float bb = bo[col];
#pragma unroll
        for (int rt=0; rt<4; rt++){
#pragma unroll
            for (int r4=0; r4<4; r4++){
                int row = row0 + (rt<<4) + (quad<<2) + r4;
                if (row < NND) out[(size_t)row*128 + col] = acco[(cto<<2)+rt][r4] + bb;
            }
        }
    }
}

extern "C" void kernel_launch(void* const* d_in, const int* in_sizes, int n_in,
                              void* d_out, int out_size, void* d_ws, size_t ws_size,
                              hipStream_t stream)
{
    const float* node_attr = (const float*)d_in[0];
    const int*   edge_index= (const int*)  d_in[1];
    const float* noise = (const float*)d_in[3];
    const float* W1 = (const float*)d_in[4];
    const float* b1 = (const float*)d_in[5];
    const float* W2 = (const float*)d_in[6];
    const float* b2 = (const float*)d_in[7];
    const float* Wx = (const float*)d_in[8];
    const float* Wh = (const float*)d_in[9];
    const float* bx = (const float*)d_in[10];
    const float* bh = (const float*)d_in[11];
    const float* Wo = (const float*)d_in[12];
    const float* bo = (const float*)d_in[13];
    const int* dst = edge_index + (size_t)NND*DEG;
    float* out = (float*)d_out;
    if (ws_size < WS_NEED) return;

    char* ws = (char*)d_ws;
    float* hpre = (float*)(ws + OFF_HPRE);
    float* proj = (float*)(ws + OFF_PROJ);
    unsigned short* Xb  = (unsigned short*)(ws + OFF_XB);
    int* idxb = (int*)(ws + OFF_IDX);
    unsigned short* BqF = (unsigned short*)(ws + OFF_BQF);
    unsigned short* WoF = (unsigned short*)(ws + OFF_WOF);

    k_setup<<<dim3(6250), dim3(256), 0, stream>>>(node_attr, Xb, Wx, Wh, BqF, Wo, WoF, idxb);

    // walk phase (fp32)
    k_projall<<<dim3(782, 5), dim3(256), 0, stream>>>(node_attr, W1, b1, hpre, proj);
    k_walk4<<<dim3(3125), dim3(256), 0, stream>>>(hpre, proj, dst, W2, b2, noise, idxb);

    // GRU (all 5 steps) + output GEMM, one kernel
    k_gru5<<<dim3(782), dim3(256), 0, stream>>>(Xb, BqF, WoF, bx, bh, bo, idxb, out);
}